// Round 4
// baseline (382.478 us; speedup 1.0000x reference)
//
#include <hip/hip_runtime.h>
#include <hip/hip_bf16.h>
#include <stdint.h>

typedef unsigned short u16;
typedef unsigned int u32;

#define T_TOK 8192
#define DIN   4096
#define DOUT  4096
#define NL    16
#define NR    16
#define KX    4096              // x part of extended-K
#define K2    4416              // 4096 + 256 (Z) + 64 (bias/onehot/pad) = 69*64
#define NKT   69                // K-tiles of 64
#define GITERS 34               // main-loop iterations (2 K-tiles each); K-tile 68 in tail

typedef __attribute__((ext_vector_type(8))) __bf16 bf16x8;
typedef __attribute__((ext_vector_type(4))) float  f32x4;
typedef __attribute__((ext_vector_type(16))) float f32x16;

__device__ __forceinline__ u32 bf16rne(float f) {
    u32 x = __float_as_uint(f);
    return (x + 0x7FFFu + ((x >> 16) & 1u)) >> 16;
}
__device__ __forceinline__ u32 pack2(float a, float b) {
    return bf16rne(a) | (bf16rne(b) << 16);
}

// ---------------- pack: x -> A' cols 0..4095, W -> B' cols 0..4095 ----------------
__global__ void pack_mats(const float* __restrict__ x, const float* __restrict__ W,
                          u16* __restrict__ Abf, u16* __restrict__ Bbf) {
    const int total = (T_TOK + DOUT) * (DIN / 8);
    for (int i = blockIdx.x * blockDim.x + threadIdx.x; i < total;
         i += gridDim.x * blockDim.x) {
        int row = i >> 9;
        int c8  = (i & 511) << 3;
        const float* src;
        u16* dst;
        if (row < T_TOK) { src = x + (size_t)row * DIN; dst = Abf + (size_t)row * K2; }
        else { src = W + (size_t)(row - T_TOK) * DIN; dst = Bbf + (size_t)(row - T_TOK) * K2; }
        const float4* s = (const float4*)(src + c8);
        float4 f0 = s[0], f1 = s[1];
        uint4 u;
        u.x = pack2(f0.x, f0.y); u.y = pack2(f0.z, f0.w);
        u.z = pack2(f1.x, f1.y); u.w = pack2(f1.z, f1.w);
        *(uint4*)(dst + c8) = u;
    }
}

// ---------------- pack_small: B' extra cols + lora_a -> bf16 ----------------
#define NBEX (DOUT * 320)
__global__ void pack_small(const float* __restrict__ lora_b,
                           const float* __restrict__ base_bias,
                           const float* __restrict__ bias_st,
                           const float* __restrict__ la,
                           u16* __restrict__ Bbf, u16* __restrict__ Aabf) {
    const int total = NBEX + NL * NR * DIN / 8;
    for (int i = blockIdx.x * blockDim.x + threadIdx.x; i < total;
         i += gridDim.x * blockDim.x) {
        if (i < NBEX) {
            int o = i / 320;
            int j = i - o * 320;
            float v = 0.f;
            if (j < 256) {
                int l = j >> 4, r = j & 15;
                v = lora_b[((size_t)l * DOUT + o) * NR + r];
            } else if (j == 256) {
                v = base_bias[o];
            } else if (j < 273) {
                v = bias_st[(size_t)(j - 257) * DOUT + o];
            }
            Bbf[(size_t)o * K2 + KX + j] = (u16)bf16rne(v);
        } else {
            int c8 = (i - NBEX) << 3;
            const float4* s = (const float4*)(la + c8);
            float4 f0 = s[0], f1 = s[1];
            uint4 u;
            u.x = pack2(f0.x, f0.y); u.y = pack2(f0.z, f0.w);
            u.z = pack2(f1.x, f1.y); u.w = pack2(f1.z, f1.w);
            *(uint4*)(Aabf + c8) = u;
        }
    }
}

// ---------------- zfill: Zfull = x_bf16 @ lora_a^T via MFMA, masked write ----------------
__global__ __launch_bounds__(512) void zfill_kernel(const u16* __restrict__ Axr,
                                                    const u16* __restrict__ La,
                                                    const int* __restrict__ idx,
                                                    u16* __restrict__ Abf) {
    __shared__ u16 sX[2][64 * 64];
    __shared__ u16 sL[2][128 * 64];
    const int tid  = threadIdx.x;
    const int lane = tid & 63, wid = tid >> 6;
    const int wr = wid >> 2, wc = wid & 3;
    const int lrow = lane & 15;
    const int klo  = (lane >> 4) << 4;
    const int sxr  = (lrow & 7) << 4;
    const int kxb[2] = { klo ^ sxr, (64 + klo) ^ sxr };

    const int bt = blockIdx.x >> 1;
    const int nh = blockIdx.x & 1;

    const int r0 = tid >> 3;
    const int c4 = (tid & 7) ^ (r0 & 7);
    const u16* pX = Axr + (size_t)(bt * 64 + r0) * K2 + c4 * 8;
    const u16* pL = La + (size_t)(nh * 128 + r0) * DIN + c4 * 8;
    const u16* pL2 = La + (size_t)(nh * 128 + 64 + r0) * DIN + c4 * 8;

    f32x4 acc[2][2];
#pragma unroll
    for (int m = 0; m < 2; ++m)
#pragma unroll
        for (int n = 0; n < 2; ++n) { f32x4 z = {0.f,0.f,0.f,0.f}; acc[m][n] = z; }

#define STAGEZ(buf, kt)                                                                \
  do {                                                                                 \
    __builtin_amdgcn_global_load_lds(                                                  \
      (const __attribute__((address_space(1))) u32*)(pX + (size_t)(kt) * 64),          \
      (__attribute__((address_space(3))) u32*)(&sX[buf][tid * 8]), 16, 0, 0);          \
    __builtin_amdgcn_global_load_lds(                                                  \
      (const __attribute__((address_space(1))) u32*)(pL + (size_t)(kt) * 64),          \
      (__attribute__((address_space(3))) u32*)(&sL[buf][tid * 8]), 16, 0, 0);          \
    __builtin_amdgcn_global_load_lds(                                                  \
      (const __attribute__((address_space(1))) u32*)(pL2 + (size_t)(kt) * 64),         \
      (__attribute__((address_space(3))) u32*)(&sL[buf][4096 + tid * 8]), 16, 0, 0);   \
  } while (0)

    STAGEZ(0, 0);
    for (int kt = 0; kt < 64; ++kt) {
        const int cur = kt & 1;
        if (kt < 63) {
            STAGEZ(cur ^ 1, kt + 1);
            asm volatile("s_waitcnt vmcnt(3)" ::: "memory");
        } else {
            asm volatile("s_waitcnt vmcnt(0)" ::: "memory");
        }
        __builtin_amdgcn_sched_barrier(0);
        __builtin_amdgcn_s_barrier();
        __builtin_amdgcn_sched_barrier(0);
        const char* sx = (const char*)sX[cur];
        const char* sl = (const char*)sL[cur];
        bf16x8 a[2][2], b[2][2];
#pragma unroll
        for (int m = 0; m < 2; ++m)
#pragma unroll
            for (int kk = 0; kk < 2; ++kk)
                a[m][kk] = *(const bf16x8*)(sx + (wr * 32 + m * 16 + lrow) * 128 + kxb[kk]);
#pragma unroll
        for (int n = 0; n < 2; ++n)
#pragma unroll
            for (int kk = 0; kk < 2; ++kk)
                b[n][kk] = *(const bf16x8*)(sl + (wc * 32 + n * 16 + lrow) * 128 + kxb[kk]);
#pragma unroll
        for (int m = 0; m < 2; ++m)
#pragma unroll
            for (int n = 0; n < 2; ++n)
#pragma unroll
                for (int kk = 0; kk < 2; ++kk)
                    acc[m][n] = __builtin_amdgcn_mfma_f32_16x16x32_bf16(
                        a[m][kk], b[n][kk], acc[m][n], 0, 0, 0);
        __builtin_amdgcn_sched_barrier(0);
        __builtin_amdgcn_s_barrier();
        __builtin_amdgcn_sched_barrier(0);
    }

#pragma unroll
    for (int m = 0; m < 2; ++m) {
#pragma unroll
        for (int rg = 0; rg < 4; ++rg) {
            int tl = wr * 32 + m * 16 + ((lane >> 4) << 2) + rg;
            int t  = bt * 64 + tl;
            int l  = idx[t];
#pragma unroll
            for (int n = 0; n < 2; ++n) {
                int col = nh * 128 + wc * 32 + n * 16 + (lane & 15);
                u16 v = ((col >> 4) == l) ? (u16)bf16rne(acc[m][n][rg]) : (u16)0;
                Abf[(size_t)t * K2 + KX + col] = v;
            }
        }
    }
    if (nh == 0) {
        int tl = tid >> 3, c8 = (tid & 7) * 8;
        int t = bt * 64 + tl;
        int l = idx[t];
        u32 w[4];
#pragma unroll
        for (int q = 0; q < 4; ++q) {
            int c0 = KX + 256 + c8 + 2 * q;
            u32 v0 = (c0 == 4352 || (l >= 0 && c0 == 4353 + l)) ? 0x3F80u : 0u;
            int c1 = c0 + 1;
            u32 v1 = (c1 == 4352 || (l >= 0 && c1 == 4353 + l)) ? 0x3F80u : 0u;
            w[q] = v0 | (v1 << 16);
        }
        *(uint4*)(Abf + (size_t)t * K2 + KX + 256 + c8) = *(uint4*)w;
    }
}

// ---------------- main GEMM: 256x256 tile, 8-phase schedule, 32x32x16 MFMA ----------------
// 8 waves (2M x 4N), BK=64, 128 KiB LDS. Same staging/vmcnt/swizzle as r3; only
// the fragment reads + MFMA shape + epilogue layout changed (16x16x32 -> 32x32x16).

#define SBAR() __builtin_amdgcn_sched_barrier(0)
#define HWBAR() __builtin_amdgcn_s_barrier()
#define PHASE_BAR() do { SBAR(); HWBAR(); SBAR(); } while (0)
#define VMCNT4() asm volatile("s_waitcnt vmcnt(4)" ::: "memory")
#define VMCNT0() asm volatile("s_waitcnt vmcnt(0)" ::: "memory")

#define STAGE(ptr, h, buf, seg, kt)                                                   \
  do { if ((kt) < NKT) {                                                              \
    __builtin_amdgcn_global_load_lds(                                                 \
      (const __attribute__((address_space(1))) u32*)((ptr) + (size_t)((h)*128 + 0)*K2 + (size_t)(kt)*64),  \
      (__attribute__((address_space(3))) u32*)(lds16 + ((((buf)*4+(seg))<<13) + tid*8)), 16, 0, 0);        \
    __builtin_amdgcn_global_load_lds(                                                 \
      (const __attribute__((address_space(1))) u32*)((ptr) + (size_t)((h)*128 + 64)*K2 + (size_t)(kt)*64), \
      (__attribute__((address_space(3))) u32*)(lds16 + ((((buf)*4+(seg))<<13) + tid*8 + 4096)), 16, 0, 0); \
  } } while (0)

// read one m-half of A: 2 m-tiles (32 rows each) x 4 k-steps = 8 ds_read_b128
#define RD_AH(buf, mh, aa)                                                            \
  { _Pragma("unroll") for (int mm = 0; mm < 2; ++mm)                                  \
    _Pragma("unroll") for (int s = 0; s < 4; ++s)                                     \
      aa[mm][s] = *(const bf16x8*)(smem + (((buf)*4 + wr) << 14)                      \
          + ((mh)*2 + mm)*4096 + lrow32*128 + kxb32[s]); }

// read one n-half of B: 1 n-tile (32 cols) x 4 k-steps = 4 ds_read_b128
#define RD_BH(buf, nh, bf)                                                            \
  { _Pragma("unroll") for (int s = 0; s < 4; ++s)                                     \
      bf[s] = *(const bf16x8*)(smem + (((buf)*4 + 2 + (wc>>1)) << 14)                 \
          + ((wc&1)*64 + (nh)*32 + lrow32)*128 + kxb32[s]); }

// one quadrant x K=64: 2 m-tiles x 1 n-tile x 4 k-steps = 8 MFMA 32x32x16
#define MMQ(mh, nh, aa, bf)                                                           \
  { __builtin_amdgcn_s_setprio(1);                                                    \
    _Pragma("unroll") for (int mm = 0; mm < 2; ++mm)                                  \
    _Pragma("unroll") for (int s = 0; s < 4; ++s)                                     \
      acc[(mh)*2+mm][nh] = __builtin_amdgcn_mfma_f32_32x32x16_bf16(                   \
          aa[mm][s], bf[s], acc[(mh)*2+mm][nh], 0, 0, 0);                             \
    __builtin_amdgcn_s_setprio(0); }

__global__ __launch_bounds__(512, 2) void gemm_kernel(const u16* __restrict__ A,
                                                      const u16* __restrict__ B,
                                                      float* __restrict__ C) {
    __shared__ u16 lds16[65536];                 // 128 KiB
    const char* smem = (const char*)lds16;

    const int tid  = threadIdx.x;
    const int lane = tid & 63, wid = tid >> 6;
    const int wr = wid >> 2, wc = wid & 3;       // 2M x 4N wave grid
    const int lrow32 = lane & 31;                // A-row / B-col within 32-tile
    const int khalf  = (lane >> 5) << 4;         // k byte-offset 0/16
    const int sx32   = (lane & 7) << 4;          // XOR swizzle key = (row&7)<<4
    const int kxb32[4] = { (0  + khalf) ^ sx32, (32 + khalf) ^ sx32,
                           (64 + khalf) ^ sx32, (96 + khalf) ^ sx32 };

    // XCD-aware swizzle: 512 blocks, 512 % 8 == 0 -> bijective
    const int wg  = blockIdx.x;
    const int swz = (wg & 7) * 64 + (wg >> 3);
    const int bm = swz >> 4;                     // 32 row-tiles
    const int bn = swz & 15;                     // 16 col-tiles

    const int r0  = tid >> 3;
    const int sc4 = (tid & 7) ^ (r0 & 7);
    const u16* pA = A + (size_t)(bm * 256 + r0) * K2 + sc4 * 8;
    const u16* pB = B + (size_t)(bn * 256 + r0) * K2 + sc4 * 8;

    f32x16 acc[4][2];
#pragma unroll
    for (int m = 0; m < 4; ++m)
#pragma unroll
        for (int n = 0; n < 2; ++n) {
            f32x16 z = {0.f,0.f,0.f,0.f,0.f,0.f,0.f,0.f,
                        0.f,0.f,0.f,0.f,0.f,0.f,0.f,0.f};
            acc[m][n] = z;
        }
    bf16x8 a0[2][4], a1[2][4], bA[4], bB[4];

    // prologue: K0 all 4 segs (buf0) + K1 A segs (buf1); K1 B staged ph1/ph2
    STAGE(pA, 0, 0, 0, 0); STAGE(pA, 1, 0, 1, 0);
    STAGE(pB, 0, 0, 2, 0); STAGE(pB, 1, 0, 3, 0);
    STAGE(pA, 0, 1, 0, 1); STAGE(pA, 1, 1, 1, 1);
    VMCNT4();                                    // 12 out -> K0's 8 landed
    PHASE_BAR();

    for (int i = 0; i < GITERS; ++i) {
        const int k1 = 2 * i + 1, kn = 2 * i + 2, kn1 = 2 * i + 3;
        // ph1: K(2i) (mh0,nh0); stage K(2i+1).B0 -> b1
        RD_AH(0, 0, a0); RD_BH(0, 0, bA);
        STAGE(pB, 0, 1, 2, k1);
        PHASE_BAR();
        MMQ(0, 0, a0, bA);
        PHASE_BAR();
        // ph2: (mh1,nh0); stage K(2i+1).B1 -> b1
        RD_AH(0, 1, a1);
        STAGE(pB, 1, 1, 3, k1);
        PHASE_BAR();
        MMQ(1, 0, a1, bA);
        PHASE_BAR();
        // ph3: (mh0,nh1); stage K(2i+2).A0 -> b0
        RD_BH(0, 1, bB);
        STAGE(pA, 0, 0, 0, kn);
        PHASE_BAR();
        MMQ(0, 1, a0, bB);
        PHASE_BAR();
        // ph4: (mh1,nh1); stage K(2i+2).A1 -> b0; guard K(2i+1) landed
        STAGE(pA, 1, 0, 1, kn);
        PHASE_BAR();
        MMQ(1, 1, a1, bB);
        VMCNT4();
        PHASE_BAR();
        // ph5: K(2i+1) (mh0,nh0); stage K(2i+2).B0 -> b0
        RD_AH(1, 0, a0); RD_BH(1, 0, bA);
        STAGE(pB, 0, 0, 2, kn);
        PHASE_BAR();
        MMQ(0, 0, a0, bA);
        PHASE_BAR();
        // ph6: (mh1,nh0); stage K(2i+2).B1 -> b0
        RD_AH(1, 1, a1);
        STAGE(pB, 1, 0, 3, kn);
        PHASE_BAR();
        MMQ(1, 0, a1, bA);
        PHASE_BAR();
        // ph7: (mh0,nh1); stage K(2i+3).A0 -> b1
        RD_BH(1, 1, bB);
        STAGE(pA, 0, 1, 0, kn1);
        PHASE_BAR();
        MMQ(0, 1, a0, bB);
        PHASE_BAR();
        // ph8: (mh1,nh1); stage K(2i+3).A1 -> b1; guard K(2i+2) landed
        STAGE(pA, 1, 1, 1, kn1);
        PHASE_BAR();
        MMQ(1, 1, a1, bB);
        VMCNT4();
        PHASE_BAR();
    }

    // tail: K-tile 68 (buf0), staged during iter 33 ph3-6
    VMCNT0();
    PHASE_BAR();
    RD_AH(0, 0, a0); RD_AH(0, 1, a1); RD_BH(0, 0, bA); RD_BH(0, 1, bB);
    MMQ(0, 0, a0, bA); MMQ(1, 0, a1, bA); MMQ(0, 1, a0, bB); MMQ(1, 1, a1, bB);

    // epilogue: 32x32 C/D layout: col = lane&31, row = (reg&3) + 8*(reg>>2) + 4*(lane>>5)
    const int erow0 = bm * 256 + wr * 128 + ((lane >> 5) << 2);
    const int ecol0 = bn * 256 + wc * 64 + (lane & 31);
#pragma unroll
    for (int mt = 0; mt < 4; ++mt)
#pragma unroll
        for (int nt = 0; nt < 2; ++nt)
#pragma unroll
            for (int rg = 0; rg < 16; ++rg) {
                int row = erow0 + mt * 32 + (rg & 3) + ((rg >> 2) << 3);
                C[(size_t)row * DOUT + ecol0 + nt * 32] = acc[mt][nt][rg];
            }
}

// ---------------- launch ----------------

extern "C" void kernel_launch(void* const* d_in, const int* in_sizes, int n_in,
                              void* d_out, int out_size, void* d_ws, size_t ws_size,
                              hipStream_t stream) {
    const float* x         = (const float*)d_in[0];
    const float* W         = (const float*)d_in[1];
    const float* base_bias = (const float*)d_in[2];
    const float* lora_a    = (const float*)d_in[3];
    const float* lora_b    = (const float*)d_in[4];
    const float* bias_st   = (const float*)d_in[5];
    const int*   indices   = (const int*)d_in[6];
    float* out = (float*)d_out;

    u16* Abf  = (u16*)d_ws;                         // [T_TOK][K2] bf16
    u16* Bbf  = Abf + (size_t)T_TOK * K2;           // [DOUT][K2] bf16
    u16* Aabf = Bbf + (size_t)DOUT * K2;            // [256][DIN] bf16 lora_a

    pack_mats<<<6144, 256, 0, stream>>>(x, W, Abf, Bbf);
    pack_small<<<1536, 256, 0, stream>>>(lora_b, base_bias, bias_st, lora_a, Bbf, Aabf);
    zfill_kernel<<<256, 512, 0, stream>>>(Abf, Aabf, indices, Abf);
    gemm_kernel<<<512, 512, 0, stream>>>(Abf, Bbf, out);
    (void)in_sizes; (void)n_in; (void)out_size; (void)ws_size;
}

// Round 5
// 341.475 us; speedup vs baseline: 1.1201x; 1.1201x over previous
//
#include <hip/hip_runtime.h>
#include <hip/hip_bf16.h>
#include <stdint.h>

typedef unsigned short u16;
typedef unsigned int u32;

#define T_TOK 8192
#define DIN   4096
#define DOUT  4096
#define NL    16
#define NR    16
#define KX    4096              // x part of extended-K
#define K2    4416              // 4096 + 256 (Z) + 64 (bias/onehot/pad) = 69*64
#define NKT   69                // K-tiles of 64
#define GITERS 34               // main-loop iterations (2 K-tiles each); K-tile 68 in tail

typedef __attribute__((ext_vector_type(8))) __bf16 bf16x8;
typedef __attribute__((ext_vector_type(4))) float  f32x4;

__device__ __forceinline__ u32 bf16rne(float f) {
    u32 x = __float_as_uint(f);
    return (x + 0x7FFFu + ((x >> 16) & 1u)) >> 16;
}
__device__ __forceinline__ u32 pack2(float a, float b) {
    return bf16rne(a) | (bf16rne(b) << 16);
}

// ---------------- pack: x -> A' cols 0..4095, W -> B' cols 0..4095 ----------------
__global__ void pack_mats(const float* __restrict__ x, const float* __restrict__ W,
                          u16* __restrict__ Abf, u16* __restrict__ Bbf) {
    const int total = (T_TOK + DOUT) * (DIN / 8);
    for (int i = blockIdx.x * blockDim.x + threadIdx.x; i < total;
         i += gridDim.x * blockDim.x) {
        int row = i >> 9;
        int c8  = (i & 511) << 3;
        const float* src;
        u16* dst;
        if (row < T_TOK) { src = x + (size_t)row * DIN; dst = Abf + (size_t)row * K2; }
        else { src = W + (size_t)(row - T_TOK) * DIN; dst = Bbf + (size_t)(row - T_TOK) * K2; }
        const float4* s = (const float4*)(src + c8);
        float4 f0 = s[0], f1 = s[1];
        uint4 u;
        u.x = pack2(f0.x, f0.y); u.y = pack2(f0.z, f0.w);
        u.z = pack2(f1.x, f1.y); u.w = pack2(f1.z, f1.w);
        *(uint4*)(dst + c8) = u;
    }
}

// ---------------- pack_small: B' extra cols + lora_a -> bf16 ----------------
#define NBEX (DOUT * 320)
__global__ void pack_small(const float* __restrict__ lora_b,
                           const float* __restrict__ base_bias,
                           const float* __restrict__ bias_st,
                           const float* __restrict__ la,
                           u16* __restrict__ Bbf, u16* __restrict__ Aabf) {
    const int total = NBEX + NL * NR * DIN / 8;
    for (int i = blockIdx.x * blockDim.x + threadIdx.x; i < total;
         i += gridDim.x * blockDim.x) {
        if (i < NBEX) {
            int o = i / 320;
            int j = i - o * 320;
            float v = 0.f;
            if (j < 256) {
                int l = j >> 4, r = j & 15;
                v = lora_b[((size_t)l * DOUT + o) * NR + r];
            } else if (j == 256) {
                v = base_bias[o];
            } else if (j < 273) {
                v = bias_st[(size_t)(j - 257) * DOUT + o];
            }
            Bbf[(size_t)o * K2 + KX + j] = (u16)bf16rne(v);
        } else {
            int c8 = (i - NBEX) << 3;
            const float4* s = (const float4*)(la + c8);
            float4 f0 = s[0], f1 = s[1];
            uint4 u;
            u.x = pack2(f0.x, f0.y); u.y = pack2(f0.z, f0.w);
            u.z = pack2(f1.x, f1.y); u.w = pack2(f1.z, f1.w);
            *(uint4*)(Aabf + c8) = u;
        }
    }
}

// ---------------- zfill: Zfull = x_bf16 @ lora_a^T via MFMA, masked write ----------------
__global__ __launch_bounds__(512) void zfill_kernel(const u16* __restrict__ Axr,
                                                    const u16* __restrict__ La,
                                                    const int* __restrict__ idx,
                                                    u16* __restrict__ Abf) {
    __shared__ u16 sX[2][64 * 64];
    __shared__ u16 sL[2][128 * 64];
    const int tid  = threadIdx.x;
    const int lane = tid & 63, wid = tid >> 6;
    const int wr = wid >> 2, wc = wid & 3;
    const int lrow = lane & 15;
    const int klo  = (lane >> 4) << 4;
    const int sxr  = (lrow & 7) << 4;
    const int kxb[2] = { klo ^ sxr, (64 + klo) ^ sxr };

    const int bt = blockIdx.x >> 1;
    const int nh = blockIdx.x & 1;

    const int r0 = tid >> 3;
    const int c4 = (tid & 7) ^ (r0 & 7);
    const u16* pX = Axr + (size_t)(bt * 64 + r0) * K2 + c4 * 8;
    const u16* pL = La + (size_t)(nh * 128 + r0) * DIN + c4 * 8;
    const u16* pL2 = La + (size_t)(nh * 128 + 64 + r0) * DIN + c4 * 8;

    f32x4 acc[2][2];
#pragma unroll
    for (int m = 0; m < 2; ++m)
#pragma unroll
        for (int n = 0; n < 2; ++n) { f32x4 z = {0.f,0.f,0.f,0.f}; acc[m][n] = z; }

#define STAGEZ(buf, kt)                                                                \
  do {                                                                                 \
    __builtin_amdgcn_global_load_lds(                                                  \
      (const __attribute__((address_space(1))) u32*)(pX + (size_t)(kt) * 64),          \
      (__attribute__((address_space(3))) u32*)(&sX[buf][tid * 8]), 16, 0, 0);          \
    __builtin_amdgcn_global_load_lds(                                                  \
      (const __attribute__((address_space(1))) u32*)(pL + (size_t)(kt) * 64),          \
      (__attribute__((address_space(3))) u32*)(&sL[buf][tid * 8]), 16, 0, 0);          \
    __builtin_amdgcn_global_load_lds(                                                  \
      (const __attribute__((address_space(1))) u32*)(pL2 + (size_t)(kt) * 64),         \
      (__attribute__((address_space(3))) u32*)(&sL[buf][4096 + tid * 8]), 16, 0, 0);   \
  } while (0)

    STAGEZ(0, 0);
    for (int kt = 0; kt < 64; ++kt) {
        const int cur = kt & 1;
        if (kt < 63) {
            STAGEZ(cur ^ 1, kt + 1);
            asm volatile("s_waitcnt vmcnt(3)" ::: "memory");
        } else {
            asm volatile("s_waitcnt vmcnt(0)" ::: "memory");
        }
        __builtin_amdgcn_sched_barrier(0);
        __builtin_amdgcn_s_barrier();
        __builtin_amdgcn_sched_barrier(0);
        const char* sx = (const char*)sX[cur];
        const char* sl = (const char*)sL[cur];
        bf16x8 a[2][2], b[2][2];
#pragma unroll
        for (int m = 0; m < 2; ++m)
#pragma unroll
            for (int kk = 0; kk < 2; ++kk)
                a[m][kk] = *(const bf16x8*)(sx + (wr * 32 + m * 16 + lrow) * 128 + kxb[kk]);
#pragma unroll
        for (int n = 0; n < 2; ++n)
#pragma unroll
            for (int kk = 0; kk < 2; ++kk)
                b[n][kk] = *(const bf16x8*)(sl + (wc * 32 + n * 16 + lrow) * 128 + kxb[kk]);
#pragma unroll
        for (int m = 0; m < 2; ++m)
#pragma unroll
            for (int n = 0; n < 2; ++n)
#pragma unroll
                for (int kk = 0; kk < 2; ++kk)
                    acc[m][n] = __builtin_amdgcn_mfma_f32_16x16x32_bf16(
                        a[m][kk], b[n][kk], acc[m][n], 0, 0, 0);
        __builtin_amdgcn_sched_barrier(0);
        __builtin_amdgcn_s_barrier();
        __builtin_amdgcn_sched_barrier(0);
    }

#pragma unroll
    for (int m = 0; m < 2; ++m) {
#pragma unroll
        for (int rg = 0; rg < 4; ++rg) {
            int tl = wr * 32 + m * 16 + ((lane >> 4) << 2) + rg;
            int t  = bt * 64 + tl;
            int l  = idx[t];
#pragma unroll
            for (int n = 0; n < 2; ++n) {
                int col = nh * 128 + wc * 32 + n * 16 + (lane & 15);
                u16 v = ((col >> 4) == l) ? (u16)bf16rne(acc[m][n][rg]) : (u16)0;
                Abf[(size_t)t * K2 + KX + col] = v;
            }
        }
    }
    if (nh == 0) {
        int tl = tid >> 3, c8 = (tid & 7) * 8;
        int t = bt * 64 + tl;
        int l = idx[t];
        u32 w[4];
#pragma unroll
        for (int q = 0; q < 4; ++q) {
            int c0 = KX + 256 + c8 + 2 * q;
            u32 v0 = (c0 == 4352 || (l >= 0 && c0 == 4353 + l)) ? 0x3F80u : 0u;
            int c1 = c0 + 1;
            u32 v1 = (c1 == 4352 || (l >= 0 && c1 == 4353 + l)) ? 0x3F80u : 0u;
            w[q] = v0 | (v1 << 16);
        }
        *(uint4*)(Abf + (size_t)t * K2 + KX + 256 + c8) = *(uint4*)w;
    }
}

// ---------------- main GEMM: 256x256 tile, 8-phase, 16x16x32 MFMA, ONE barrier/phase ----
// 8 waves (2M x 4N), BK=64, 128 KiB LDS. r3 schedule, BUT single end-of-phase
// barrier: each phase's ds_reads are consumed by that phase's MMQ (lgkmcnt
// drained before use), so read-completion is implied at the barrier; staged
// segs were last read one phase earlier -> safe. vmcnt(4) before the ph4/ph8
// barriers proves the next-needed K-tile's DMAs landed across all waves.

#define SBAR() __builtin_amdgcn_sched_barrier(0)
#define HWBAR() __builtin_amdgcn_s_barrier()
#define PHASE_BAR() do { SBAR(); HWBAR(); SBAR(); } while (0)
#define VMCNT4() asm volatile("s_waitcnt vmcnt(4)" ::: "memory")
#define VMCNT0() asm volatile("s_waitcnt vmcnt(0)" ::: "memory")

#define STAGE(ptr, h, buf, seg, kt)                                                   \
  do { if ((kt) < NKT) {                                                              \
    __builtin_amdgcn_global_load_lds(                                                 \
      (const __attribute__((address_space(1))) u32*)((ptr) + (size_t)((h)*128 + 0)*K2 + (size_t)(kt)*64),  \
      (__attribute__((address_space(3))) u32*)(lds16 + ((((buf)*4+(seg))<<13) + tid*8)), 16, 0, 0);        \
    __builtin_amdgcn_global_load_lds(                                                 \
      (const __attribute__((address_space(1))) u32*)((ptr) + (size_t)((h)*128 + 64)*K2 + (size_t)(kt)*64), \
      (__attribute__((address_space(3))) u32*)(lds16 + ((((buf)*4+(seg))<<13) + tid*8 + 4096)), 16, 0, 0); \
  } } while (0)

// read one m-half of A (4 frags x 2 k-chunks = 8 ds_read_b128)
#define RD_AH(buf, mh, aa)                                                            \
  { _Pragma("unroll") for (int mm = 0; mm < 4; ++mm)                                  \
    _Pragma("unroll") for (int kk = 0; kk < 2; ++kk)                                  \
      aa[mm][kk] = *(const bf16x8*)(smem + (((buf)*4 + wr) << 14) + lrow*128          \
          + (mh)*8192 + mm*2048 + kxb[kk]); }

// read one n-half of B (2 frags x 2 k-chunks = 4 ds_read_b128)
#define RD_BH(buf, nh, bf)                                                            \
  { _Pragma("unroll") for (int nn = 0; nn < 2; ++nn)                                  \
    _Pragma("unroll") for (int kk = 0; kk < 2; ++kk)                                  \
      bf[nn][kk] = *(const bf16x8*)(smem + (((buf)*4 + 2 + (wc>>1)) << 14)            \
          + ((wc&1)*64 + lrow)*128 + ((nh)*2+nn)*2048 + kxb[kk]); }

#define MMQ(mh, nh, aa, bf)                                                           \
  { __builtin_amdgcn_s_setprio(1);                                                    \
    _Pragma("unroll") for (int mm = 0; mm < 4; ++mm)                                  \
    _Pragma("unroll") for (int nn = 0; nn < 2; ++nn)                                  \
    _Pragma("unroll") for (int kk = 0; kk < 2; ++kk)                                  \
      acc[(mh)*4+mm][(nh)*2+nn] = __builtin_amdgcn_mfma_f32_16x16x32_bf16(            \
          aa[mm][kk], bf[nn][kk], acc[(mh)*4+mm][(nh)*2+nn], 0, 0, 0);                \
    __builtin_amdgcn_s_setprio(0); }

__global__ __launch_bounds__(512, 2) void gemm_kernel(const u16* __restrict__ A,
                                                      const u16* __restrict__ B,
                                                      float* __restrict__ C) {
    __shared__ u16 lds16[65536];                 // 128 KiB
    const char* smem = (const char*)lds16;

    const int tid  = threadIdx.x;
    const int lane = tid & 63, wid = tid >> 6;
    const int wr = wid >> 2, wc = wid & 3;       // 2M x 4N wave grid
    const int lrow = lane & 15;
    const int klo  = (lane >> 4) << 4;
    const int sx   = (lrow & 7) << 4;
    const int kxb[2] = { klo ^ sx, (64 + klo) ^ sx };

    // XCD-aware swizzle: 512 blocks, 512 % 8 == 0 -> bijective
    const int wg  = blockIdx.x;
    const int swz = (wg & 7) * 64 + (wg >> 3);
    const int bm = swz >> 4;                     // 32 row-tiles
    const int bn = swz & 15;                     // 16 col-tiles

    const int r0  = tid >> 3;
    const int sc4 = (tid & 7) ^ (r0 & 7);
    const u16* pA = A + (size_t)(bm * 256 + r0) * K2 + sc4 * 8;
    const u16* pB = B + (size_t)(bn * 256 + r0) * K2 + sc4 * 8;

    f32x4 acc[8][4];
#pragma unroll
    for (int m = 0; m < 8; ++m)
#pragma unroll
        for (int n = 0; n < 4; ++n) { f32x4 z = {0.f,0.f,0.f,0.f}; acc[m][n] = z; }
    bf16x8 a0[4][2], a1[4][2], bA[2][2], bB[2][2];

    // prologue: K0 all 4 segs (buf0) + K1 A segs (buf1); K1 B staged ph1/ph2
    STAGE(pA, 0, 0, 0, 0); STAGE(pA, 1, 0, 1, 0);
    STAGE(pB, 0, 0, 2, 0); STAGE(pB, 1, 0, 3, 0);
    STAGE(pA, 0, 1, 0, 1); STAGE(pA, 1, 1, 1, 1);
    VMCNT4();                                    // 12 out -> K0's 8 landed
    PHASE_BAR();

    for (int i = 0; i < GITERS; ++i) {
        const int k1 = 2 * i + 1, kn = 2 * i + 2, kn1 = 2 * i + 3;
        // ph1: K(2i) (mh0,nh0); stage K(2i+1).B0 -> b1 (b1.B last read prev ph7)
        RD_AH(0, 0, a0); RD_BH(0, 0, bA);
        STAGE(pB, 0, 1, 2, k1);
        MMQ(0, 0, a0, bA);
        PHASE_BAR();
        // ph2: (mh1,nh0); stage K(2i+1).B1 -> b1
        RD_AH(0, 1, a1);
        STAGE(pB, 1, 1, 3, k1);
        MMQ(1, 0, a1, bA);
        PHASE_BAR();
        // ph3: (mh0,nh1); stage K(2i+2).A0 -> b0 (b0.A fully read in ph2)
        RD_BH(0, 1, bB);
        STAGE(pA, 0, 0, 0, kn);
        MMQ(0, 1, a0, bB);
        PHASE_BAR();
        // ph4: (mh1,nh1); stage K(2i+2).A1 -> b0; guard K(2i+1) landed
        STAGE(pA, 1, 0, 1, kn);
        MMQ(1, 1, a1, bB);
        VMCNT4();
        PHASE_BAR();
        // ph5: K(2i+1) (mh0,nh0); stage K(2i+2).B0 -> b0 (b0.B fully read in ph3)
        RD_AH(1, 0, a0); RD_BH(1, 0, bA);
        STAGE(pB, 0, 0, 2, kn);
        MMQ(0, 0, a0, bA);
        PHASE_BAR();
        // ph6: (mh1,nh0); stage K(2i+2).B1 -> b0
        RD_AH(1, 1, a1);
        STAGE(pB, 1, 0, 3, kn);
        MMQ(1, 0, a1, bA);
        PHASE_BAR();
        // ph7: (mh0,nh1); stage K(2i+3).A0 -> b1 (b1.A fully read in ph6)
        RD_BH(1, 1, bB);
        STAGE(pA, 0, 1, 0, kn1);
        MMQ(0, 1, a0, bB);
        PHASE_BAR();
        // ph8: (mh1,nh1); stage K(2i+3).A1 -> b1; guard K(2i+2) landed
        STAGE(pA, 1, 1, 1, kn1);
        MMQ(1, 1, a1, bB);
        VMCNT4();
        PHASE_BAR();
    }

    // tail: K-tile 68 (buf0), staged during iter 33 ph3-6
    VMCNT0();
    PHASE_BAR();
    RD_AH(0, 0, a0); RD_AH(0, 1, a1); RD_BH(0, 0, bA); RD_BH(0, 1, bB);
    MMQ(0, 0, a0, bA); MMQ(1, 0, a1, bA); MMQ(0, 1, a0, bB); MMQ(1, 1, a1, bB);

    // epilogue: C/D layout col = lane&15, row = (lane>>4)*4 + reg
    const int crow0 = bm * 256 + wr * 128 + ((lane >> 4) << 2);
    const int ccol0 = bn * 256 + wc * 64 + (lane & 15);
#pragma unroll
    for (int m = 0; m < 8; ++m)
#pragma unroll
        for (int n = 0; n < 4; ++n)
#pragma unroll
            for (int rg = 0; rg < 4; ++rg)
                C[(size_t)(crow0 + m * 16 + rg) * DOUT + ccol0 + n * 16] = acc[m][n][rg];
}

// ---------------- launch ----------------

extern "C" void kernel_launch(void* const* d_in, const int* in_sizes, int n_in,
                              void* d_out, int out_size, void* d_ws, size_t ws_size,
                              hipStream_t stream) {
    const float* x         = (const float*)d_in[0];
    const float* W         = (const float*)d_in[1];
    const float* base_bias = (const float*)d_in[2];
    const float* lora_a    = (const float*)d_in[3];
    const float* lora_b    = (const float*)d_in[4];
    const float* bias_st   = (const float*)d_in[5];
    const int*   indices   = (const int*)d_in[6];
    float* out = (float*)d_out;

    u16* Abf  = (u16*)d_ws;                         // [T_TOK][K2] bf16
    u16* Bbf  = Abf + (size_t)T_TOK * K2;           // [DOUT][K2] bf16
    u16* Aabf = Bbf + (size_t)DOUT * K2;            // [256][DIN] bf16 lora_a

    pack_mats<<<6144, 256, 0, stream>>>(x, W, Abf, Bbf);
    pack_small<<<1536, 256, 0, stream>>>(lora_b, base_bias, bias_st, lora_a, Bbf, Aabf);
    zfill_kernel<<<256, 512, 0, stream>>>(Abf, Aabf, indices, Abf);
    gemm_kernel<<<512, 512, 0, stream>>>(Abf, Bbf, out);
    (void)in_sizes; (void)n_in; (void)out_size; (void)ws_size;
}